// Round 2
// 1005.799 us; speedup vs baseline: 1.8712x; 1.8712x over previous
//
#include <hip/hip_runtime.h>
#include <math.h>

// Problem constants (match reference)
constexpr int Bb = 64;
constexpr int T  = 1024;
constexpr int DK = 64;
constexpr int QT = 8;      // q rows per block
constexpr int KT = 128;    // k rows per score tile
constexpr int NTL = T / KT;    // 8 tiles
constexpr int KP4 = 17;    // padded K-tile row pitch in float4 (breaks bank aliasing; 0 conflicts measured)
constexpr float MASK_FILL_F = -4294967295.0f;  // float(-2^32+1)

typedef float vfloat4 __attribute__((ext_vector_type(4)));  // native vec for nontemporal builtin

__device__ __forceinline__ float4 shfl_xor_f4(float4 v, int m) {
    v.x = __shfl_xor(v.x, m, 64);
    v.y = __shfl_xor(v.y, m, 64);
    v.z = __shfl_xor(v.z, m, 64);
    v.w = __shfl_xor(v.w, m, 64);
    return v;
}

// LDS budget: sK4 34816 B + sQ4 2048 B = 36864 B  ->  4 blocks/CU (16 waves, ~48% occ)
// Overlays inside sK4 region (pass 2 only; region dead as K-tile by then):
//   sP    = floats [0    .. 1024)   per-tile probability tile [QT][KT]
//   red   = float4 [512  .. 1024)   epilogue cross-wave reduction buffer
//   stats = floats [4096 .. 4128)   per-wave (m,l) softmax partials
__global__ __launch_bounds__(256, 4)
void mha_fused_kernel(const float* __restrict__ Kp,   // key   [B,T,DK]
                      const float* __restrict__ Vp,   // value [B,T,DK]
                      const float* __restrict__ Qp,   // query [B,T,DK]
                      const int*   __restrict__ maskp,// mask  [B,T,T] (bool as i32)
                      const float* __restrict__ qmp,  // query_mask [B,T,T]
                      const float* __restrict__ gfp,  // gaussian_factor [B,T,T]
                      float* __restrict__ out_res,    // [B,T,DK]
                      float* __restrict__ out_attn)   // [B,T,T]
{
    __shared__ float4 sK4[KT * KP4];   // 34816 B
    __shared__ float4 sQ4[QT * 16];    // 2048 B

    const int b    = blockIdx.y;
    const int q0   = blockIdx.x * QT;
    const int tid  = threadIdx.x;
    const int kl   = tid & 127;        // k within tile (pass-1 mapping)
    const int qh   = tid >> 7;         // 0..1 -> q group 4*qh .. 4*qh+3
    const int lane = tid & 63;
    const int wv   = tid >> 6;

    // ---- Load Q tile ----
    const float4* Qg4 = reinterpret_cast<const float4*>(Qp + (b * T + q0) * DK);
    if (tid < QT * 16) sQ4[tid] = Qg4[tid];

    const int ib0 = (b * T + q0 + qh * 4) * T + kl;   // [B,T,T] base for pass-1 mapping (< 2^27, fits int)

    // prefetch tile-0 gf/mask (in flight under Q + first K staging; drained at first barrier)
    float gfv[4]; int mkv[4];
    #pragma unroll
    for (int j = 0; j < 4; ++j) {
        gfv[j] = gfp[ib0 + j * T];
        mkv[j] = maskp[ib0 + j * T];
    }

    float mrun[4], lrun[4];
    #pragma unroll
    for (int j = 0; j < 4; ++j) { mrun[j] = -INFINITY; lrun[j] = 0.0f; }

    // ================= pass 1: raw masked scores -> out_attn, online (m,l) =================
    #pragma unroll 1
    for (int kt = 0; kt < NTL; ++kt) {
        __syncthreads();   // kt=0: Q visible; kt>0: prev tile's sK reads done
        const float4* Kg4 = reinterpret_cast<const float4*>(Kp + (b * T + kt * KT) * DK);
        #pragma unroll
        for (int i = 0; i < 8; ++i) {
            const int fi = tid + i * 256;
            sK4[(fi >> 4) * KP4 + (fi & 15)] = Kg4[fi];
        }
        __syncthreads();

        // prefetch NEXT tile's gf/mask: in flight during this tile's compute
        const int ktn = (kt + 1) & (NTL - 1);
        float gfn[4]; int mkn[4];
        #pragma unroll
        for (int j = 0; j < 4; ++j) {
            gfn[j] = gfp[ib0 + j * T + ktn * KT];
            mkn[j] = maskp[ib0 + j * T + ktn * KT];
        }

        float4 acc[4];
        #pragma unroll
        for (int j = 0; j < 4; ++j) acc[j] = make_float4(0.f, 0.f, 0.f, 0.f);
        #pragma unroll
        for (int dd = 0; dd < 16; ++dd) {
            const float4 kv = sK4[kl * KP4 + dd];
            #pragma unroll
            for (int j = 0; j < 4; ++j) {
                const float4 qv = sQ4[(qh * 4 + j) * 16 + dd];  // wave-uniform -> broadcast
                acc[j].x += kv.x * qv.x;
                acc[j].y += kv.y * qv.y;
                acc[j].z += kv.z * qv.z;
                acc[j].w += kv.w * qv.w;
            }
        }

        #pragma unroll
        for (int j = 0; j < 4; ++j) {
            float sv = (acc[j].x + acc[j].y + acc[j].z + acc[j].w) * 0.125f - gfv[j];
            if (mkv[j] != 0) sv = MASK_FILL_F;
            out_attn[ib0 + j * T + kt * KT] = sv;     // raw masked score (overwritten in pass 2)
            const float mn = fmaxf(mrun[j], sv);      // online softmax update
            lrun[j] = lrun[j] * __expf(mrun[j] - mn) + __expf(sv - mn);
            mrun[j] = mn;
            gfv[j] = gfn[j];
            mkv[j] = mkn[j];
        }
    }

    // ---- prefetch pass-2 tile 0 (vectorized mapping); tile-0 raw stores drained many barriers ago ----
    const int qq  = tid >> 5;          // 0..7: row owned in pass 2
    const int kc  = tid & 31;          // float4 column within tile
    const int ib2 = (b * T + q0 + qq) * T + kc * 4;
    float4 rawv = *reinterpret_cast<const float4*>(&out_attn[ib2]);
    float4 qmv  = *reinterpret_cast<const float4*>(&qmp[ib2]);

    // ================= softmax stats reduction =================
    #pragma unroll
    for (int j = 0; j < 4; ++j) {
        #pragma unroll
        for (int off = 32; off; off >>= 1) {
            const float mo = __shfl_xor(mrun[j], off, 64);
            const float lo = __shfl_xor(lrun[j], off, 64);
            const float mn = fmaxf(mrun[j], mo);
            lrun[j] = lrun[j] * __expf(mrun[j] - mn) + lo * __expf(mo - mn);
            mrun[j] = mn;
        }
    }
    float* sF    = reinterpret_cast<float*>(sK4);
    float* stats = sF + 4096;          // clear of sP and red regions
    __syncthreads();                   // all sK reads done before overlay write
    if (lane == 0) {
        #pragma unroll
        for (int j = 0; j < 4; ++j) {
            stats[(wv * 4 + j) * 2 + 0] = mrun[j];
            stats[(wv * 4 + j) * 2 + 1] = lrun[j];
        }
    }
    __syncthreads();                   // also guarantees ALL pass-1 raw stores drained

    // per-thread constants for its pass-2 row qq: combine the 2 wave partials
    const int j2 = qq & 3, qg = qq >> 2;
    const float m0 = stats[((qg * 2 + 0) * 4 + j2) * 2 + 0];
    const float l0 = stats[((qg * 2 + 0) * 4 + j2) * 2 + 1];
    const float m1 = stats[((qg * 2 + 1) * 4 + j2) * 2 + 0];
    const float l1 = stats[((qg * 2 + 1) * 4 + j2) * 2 + 1];
    const float M2   = fmaxf(m0, m1);
    const float inv2 = 1.0f / (l0 * __expf(m0 - M2) + l1 * __expf(m1 - M2));

    // ================= pass 2: probs (float4) + PV =================
    const int d4  = tid & 15;
    const int kg2 = tid >> 4;
    const float4* Vg4 = reinterpret_cast<const float4*>(Vp + b * T * DK);
    float* sP = sF;                    // floats [0..1024): [QT][KT] prob tile

    float4 acc2[QT];
    #pragma unroll
    for (int q = 0; q < QT; ++q) acc2[q] = make_float4(0.f, 0.f, 0.f, 0.f);

    #pragma unroll 1
    for (int kt = 0; kt < NTL; ++kt) {
        vfloat4 p4;
        p4.x = __expf(rawv.x - M2) * inv2 * qmv.x;
        p4.y = __expf(rawv.y - M2) * inv2 * qmv.y;
        p4.z = __expf(rawv.z - M2) * inv2 * qmv.z;
        p4.w = __expf(rawv.w - M2) * inv2 * qmv.w;
        __builtin_nontemporal_store(p4, reinterpret_cast<vfloat4*>(&out_attn[ib2 + kt * KT]));
        *reinterpret_cast<vfloat4*>(&sP[qq * KT + kc * 4]) = p4;
        __syncthreads();

        // prefetch next tile's raw scores + qm: hidden under PV (kt=7 wraps -> discarded)
        const int ktn = (kt + 1) & (NTL - 1);
        const float4 rawn = *reinterpret_cast<const float4*>(&out_attn[ib2 + ktn * KT]);
        const float4 qmn  = *reinterpret_cast<const float4*>(&qmp[ib2 + ktn * KT]);

        #pragma unroll
        for (int i = 0; i < 8; ++i) {
            const int kk = i * 16 + kg2;
            const float4 vv = Vg4[(kt * KT + kk) * 16 + d4];  // wave reads 1KB contiguous (L2-hot)
            #pragma unroll
            for (int q = 0; q < QT; ++q) {
                const float p = sP[q * KT + kk];              // 4 addrs/wave, broadcast, conflict-free
                acc2[q].x += p * vv.x;
                acc2[q].y += p * vv.y;
                acc2[q].z += p * vv.z;
                acc2[q].w += p * vv.w;
            }
        }
        rawv = rawn; qmv = qmn;
        __syncthreads();
    }

    // ---- epilogue: intra-wave reduce over 4 k-residues (kg2 bits = lane bits 4..5) ----
    #pragma unroll
    for (int q = 0; q < QT; ++q) {
        float4 t = shfl_xor_f4(acc2[q], 16);
        acc2[q].x += t.x; acc2[q].y += t.y; acc2[q].z += t.z; acc2[q].w += t.w;
        t = shfl_xor_f4(acc2[q], 32);
        acc2[q].x += t.x; acc2[q].y += t.y; acc2[q].z += t.z; acc2[q].w += t.w;
    }

    float4* red = sK4 + 512;           // floats [2048..4096): disjoint from sP
    if (lane < 16) {
        #pragma unroll
        for (int q = 0; q < QT; ++q)
            red[(wv * QT + q) * 16 + lane] = acc2[q];
    }
    __syncthreads();

    if (tid < 128) {
        const int q  = tid >> 4;
        const int dd = tid & 15;
        float4 s0 = red[(0 * QT + q) * 16 + dd];
        float4 s1 = red[(1 * QT + q) * 16 + dd];
        float4 s2 = red[(2 * QT + q) * 16 + dd];
        float4 s3 = red[(3 * QT + q) * 16 + dd];
        float4 o;
        o.x = s0.x + s1.x + s2.x + s3.x;
        o.y = s0.y + s1.y + s2.y + s3.y;
        o.z = s0.z + s1.z + s2.z + s3.z;
        o.w = s0.w + s1.w + s2.w + s3.w;
        float4* Og4 = reinterpret_cast<float4*>(out_res + (b * T + q0) * DK);
        Og4[q * 16 + dd] = o;
    }
}

extern "C" void kernel_launch(void* const* d_in, const int* in_sizes, int n_in,
                              void* d_out, int out_size, void* d_ws, size_t ws_size,
                              hipStream_t stream) {
    const float* key   = (const float*)d_in[0];
    const float* value = (const float*)d_in[1];
    const float* query = (const float*)d_in[2];
    const int*   mask  = (const int*)d_in[3];
    const float* qmask = (const float*)d_in[4];
    const float* gauss = (const float*)d_in[5];

    float* out      = (float*)d_out;
    float* out_res  = out;                       // [B,T,DK]
    float* out_attn = out + Bb * T * DK;         // [B,T,T]

    dim3 grid(T / QT, Bb);
    dim3 block(256);
    mha_fused_kernel<<<grid, block, 0, stream>>>(key, value, query, mask, qmask, gauss,
                                                 out_res, out_attn);
}